// Round 10
// baseline (395.914 us; speedup 1.0000x reference)
//
#include <hip/hip_runtime.h>

// 3-layer GCN, input-dim aggregation (A(XW) = (AX)W), bucketed CSR build,
// fully fused layers. csr entries pack the dst's local index within its
// 32-node group (bits 27..31); src is in bits 0..16 (N < 2^17).
//
// layer3_pool gather: chunked (edge-balanced) assignment + straight unrolled
// LDS-atomic accumulate. Balance avoids degree stragglers; the dependency-free
// loop body restores memory-level parallelism (R9's run-length accumulator was
// serial); chunk offsets de-phase the groups so same-address LDS atomic
// collisions are rare (R8's lockstep pathology).

#define BSHIFT 9
#define BSZ 512
#define P2_TILE 2048
#define P1_BLOCKS 128
#define SRCMASK 0x1FFFF
#define NB3 32  // nodes per layer3 block

__device__ __forceinline__ unsigned fenc(float x) {
  unsigned b = __float_as_uint(x);
  return (b & 0x80000000u) ? ~b : (b | 0x80000000u);
}
__device__ __forceinline__ float fdec(unsigned k) {
  return (k & 0x80000000u) ? __uint_as_float(k ^ 0x80000000u)
                           : __uint_as_float(~k);
}

// ---------------- CSR build ----------------

__global__ __launch_bounds__(256) void p1_hist_kernel(const int* __restrict__ dst,
                                                      int* __restrict__ hist2d, int E) {
  __shared__ int h[256];
  h[threadIdx.x] = 0;
  __syncthreads();
  for (int e = blockIdx.x * blockDim.x + threadIdx.x; e < E; e += gridDim.x * blockDim.x)
    atomicAdd(&h[dst[e] >> BSHIFT], 1);
  __syncthreads();
  hist2d[blockIdx.x * 256 + threadIdx.x] = h[threadIdx.x];
}

__global__ __launch_bounds__(256) void p1_scan_kernel(const int* __restrict__ hist2d,
                                                      int* __restrict__ bucketBase,
                                                      int* __restrict__ bucketCursor,
                                                      unsigned* __restrict__ pooled,
                                                      int B, int E, int G) {
  __shared__ int s[256];
  int t = threadIdx.x;
  int v = 0;
  for (int b = 0; b < P1_BLOCKS; ++b) v += hist2d[b * 256 + t];
  if (t >= B) v = 0;
  s[t] = v;
  __syncthreads();
  for (int o = 1; o < 256; o <<= 1) {
    int u = (t >= o) ? s[t - o] : 0;
    __syncthreads();
    s[t] += u;
    __syncthreads();
  }
  int excl = s[t] - v;
  bucketBase[t] = excl;
  bucketCursor[t] = excl;
  if (t == 0) bucketBase[256] = E;
  for (int i = t; i < G * 128; i += 256) pooled[i] = 0u;  // fenc key 0 < -inf
}

__global__ __launch_bounds__(256) void p2_partition_kernel(
    const int* __restrict__ src, const int* __restrict__ dst,
    int* __restrict__ bucketCursor, unsigned* __restrict__ part, int E) {
  __shared__ int hist[256];
  __shared__ int lbase[256];
  __shared__ int gbase[256];
  __shared__ int cur[256];
  __shared__ unsigned sbuf[P2_TILE];
  __shared__ unsigned abuf[P2_TILE];
  int t = threadIdx.x;
  int e0 = blockIdx.x * P2_TILE;
  int cnt = min(P2_TILE, E - e0);

  hist[t] = 0;
  __syncthreads();

  int myb[P2_TILE / 256];
  unsigned myp[P2_TILE / 256];
#pragma unroll
  for (int k = 0; k < P2_TILE / 256; ++k) {
    int i = t + k * 256;
    if (i < cnt) {
      int e = e0 + i;
      int d = dst[e];
      int b = d >> BSHIFT;
      myb[k] = b;
      myp[k] = ((unsigned)(d & (BSZ - 1)) << 17) | (unsigned)src[e];
      atomicAdd(&hist[b], 1);
    } else {
      myb[k] = -1;
      myp[k] = 0;
    }
  }
  __syncthreads();

  int v = hist[t];
  lbase[t] = v;
  __syncthreads();
  for (int o = 1; o < 256; o <<= 1) {
    int u = (t >= o) ? lbase[t - o] : 0;
    __syncthreads();
    lbase[t] += u;
    __syncthreads();
  }
  int excl = lbase[t] - v;
  __syncthreads();
  lbase[t] = excl;
  if (v > 0) gbase[t] = atomicAdd(&bucketCursor[t], v);
  cur[t] = 0;
  __syncthreads();

#pragma unroll
  for (int k = 0; k < P2_TILE / 256; ++k) {
    int b = myb[k];
    if (b >= 0) {
      int pos = atomicAdd(&cur[b], 1);
      int li = lbase[b] + pos;
      sbuf[li] = myp[k];
      abuf[li] = (unsigned)(gbase[b] + pos);
    }
  }
  __syncthreads();

#pragma unroll
  for (int k = 0; k < P2_TILE / 256; ++k) {
    int i = t + k * 256;
    if (i < cnt) part[abuf[i]] = sbuf[i];
  }
}

__global__ __launch_bounds__(512) void p3_build_kernel(
    const unsigned* __restrict__ part, const int* __restrict__ bucketBase,
    const float* __restrict__ x, float* __restrict__ xs,
    float* __restrict__ dis, int* __restrict__ rp, unsigned* __restrict__ csr,
    int N, int B, int E) {
  __shared__ int hist[BSZ];
  __shared__ int scn[BSZ];
  int b = blockIdx.x, t = threadIdx.x;
  int base = bucketBase[b], end = bucketBase[b + 1];
  int cnt = end - base;

  hist[t] = 0;
  __syncthreads();
  for (int i = t; i < cnt; i += BSZ) atomicAdd(&hist[part[base + i] >> 17], 1);
  __syncthreads();

  int v = hist[t];
  scn[t] = v;
  __syncthreads();
  for (int o = 1; o < BSZ; o <<= 1) {
    int u = (t >= o) ? scn[t - o] : 0;
    __syncthreads();
    scn[t] += u;
    __syncthreads();
  }
  int excl = scn[t] - v;

  int n = (b << BSHIFT) + t;
  if (n < N) {
    float dn = rsqrtf((float)v + 1.0f);
    dis[n] = dn;
    rp[n] = base + excl;
    float2 xn = *reinterpret_cast<const float2*>(x + 2 * (size_t)n);
    float2 o;
    o.x = dn * xn.x;
    o.y = dn * xn.y;
    *reinterpret_cast<float2*>(xs + 2 * (size_t)n) = o;
  }
  if (b == B - 1 && t == 0) rp[N] = E;

  hist[t] = excl;
  __syncthreads();
  // csr entry: src (bits 0..16) | dst's local index within its 32-node group
  // (bits 27..31) -- derived from the EDGE's dst.
  for (int i = t; i < cnt; i += BSZ) {
    unsigned p = part[base + i];
    unsigned dl = p >> 17;  // dst local index in bucket (0..511)
    int pos = atomicAdd(&hist[dl], 1);
    csr[base + pos] = (p & SRCMASK) | ((dl & 31u) << 27);
  }
}

// ---------------- fused layers ----------------

__global__ __launch_bounds__(256) void layer1_kernel(
    const int* __restrict__ rp, const unsigned* __restrict__ csr, const float* __restrict__ dis,
    const float* __restrict__ xs, const float* __restrict__ W1, const float* __restrict__ b1,
    float* __restrict__ h1s, int N) {
  __shared__ float sW[16];
  __shared__ float sb[8];
  int t = threadIdx.x;
  if (t < 16) sW[t] = W1[t];
  if (t < 8) sb[t] = b1[t];
  __syncthreads();
  int n = blockIdx.x * blockDim.x + t;
  if (n >= N) return;
  float2 a = *reinterpret_cast<const float2*>(xs + 2 * (size_t)n);  // self
  int j0 = rp[n], j1 = rp[n + 1];
#pragma unroll 4
  for (int j = j0; j < j1; ++j) {
    int s = csr[j] & SRCMASK;
    const float2 v = *reinterpret_cast<const float2*>(xs + 2 * (size_t)s);
    a.x += v.x;
    a.y += v.y;
  }
  float dn = dis[n];
  float ax = dn * a.x, ay = dn * a.y;
  float4 o0, o1;
  float* o = &o0.x;
#pragma unroll
  for (int f = 0; f < 8; ++f)
    o[f] = dn * fmaxf(ax * sW[f] + ay * sW[8 + f] + sb[f], 0.f);
  *reinterpret_cast<float4*>(h1s + (size_t)n * 8) = o0;
  *reinterpret_cast<float4*>(h1s + (size_t)n * 8 + 4) = o1;
}

__global__ __launch_bounds__(256) void layer2_kernel(
    const int* __restrict__ rp, const unsigned* __restrict__ csr, const float* __restrict__ dis,
    const float* __restrict__ h1s, const float* __restrict__ W2, const float* __restrict__ b2,
    float* __restrict__ h2s, int N) {
  __shared__ float sW[256];  // [8][32]
  __shared__ float sb[32];
  int t = threadIdx.x;
  sW[t] = W2[t];
  if (t < 32) sb[t] = b2[t];
  __syncthreads();
  int n = blockIdx.x * blockDim.x + t;
  if (n >= N) return;
  float4 a0 = *reinterpret_cast<const float4*>(h1s + (size_t)n * 8);
  float4 a1 = *reinterpret_cast<const float4*>(h1s + (size_t)n * 8 + 4);
  int j0 = rp[n], j1 = rp[n + 1];
#pragma unroll 4
  for (int j = j0; j < j1; ++j) {
    int s = csr[j] & SRCMASK;
    const float4 v0 = *reinterpret_cast<const float4*>(h1s + (size_t)s * 8);
    const float4 v1 = *reinterpret_cast<const float4*>(h1s + (size_t)s * 8 + 4);
    a0.x += v0.x; a0.y += v0.y; a0.z += v0.z; a0.w += v0.w;
    a1.x += v1.x; a1.y += v1.y; a1.z += v1.z; a1.w += v1.w;
  }
  float dn = dis[n];
  float a2r[8] = {dn * a0.x, dn * a0.y, dn * a0.z, dn * a0.w,
                  dn * a1.x, dn * a1.y, dn * a1.z, dn * a1.w};
#pragma unroll
  for (int fc = 0; fc < 8; ++fc) {
    float4 o;
    o.x = sb[fc * 4 + 0]; o.y = sb[fc * 4 + 1]; o.z = sb[fc * 4 + 2]; o.w = sb[fc * 4 + 3];
#pragma unroll
    for (int k = 0; k < 8; ++k) {
      const float4 w = *reinterpret_cast<const float4*>(&sW[k * 32 + fc * 4]);
      float a = a2r[k];
      o.x += a * w.x; o.y += a * w.y; o.z += a * w.z; o.w += a * w.w;
    }
    o.x = dn * fmaxf(o.x, 0.f);
    o.y = dn * fmaxf(o.y, 0.f);
    o.z = dn * fmaxf(o.z, 0.f);
    o.w = dn * fmaxf(o.w, 0.f);
    *reinterpret_cast<float4*>(h2s + (size_t)n * 32 + fc * 4) = o;
  }
}

// layer3 fused: 32 nodes/block, chunked edge-balanced gather with
// dependency-free unrolled LDS-atomic accumulate, then matvec + segmented
// max-pool (rows split across thread halves, union via global atomicMax).
__global__ __launch_bounds__(256) void layer3_pool_kernel(
    const int* __restrict__ rp, const unsigned* __restrict__ csr, const float* __restrict__ dis,
    const float* __restrict__ h2s, const float* __restrict__ W3, const float* __restrict__ b3,
    const int* __restrict__ batch, unsigned* __restrict__ pooled, int N) {
  __shared__ float rows[NB3][32];
  __shared__ float dnv[NB3];
  int t = threadIdx.x;
  int gi = t >> 3;           // group 0..31
  int off = (t & 7) * 4;     // float4 lane within row

  int n0 = blockIdx.x * NB3;
  int m = min(NB3, N - n0);

  // self-term init (non-atomic) + dis cache
  if (gi < m) {
    const float4 sv = *reinterpret_cast<const float4*>(h2s + (size_t)(n0 + gi) * 32 + off);
    rows[gi][off + 0] = sv.x;
    rows[gi][off + 1] = sv.y;
    rows[gi][off + 2] = sv.z;
    rows[gi][off + 3] = sv.w;
  }
  if (t < m) dnv[t] = dis[n0 + t];
  __syncthreads();

  // chunked edge-balanced gather; loop body has no loop-carried deps -> the
  // compiler keeps multiple h2s loads in flight.
  {
    int j0 = rp[n0];
    int cnt = rp[n0 + m] - j0;
    int chunk = (cnt + NB3 - 1) / NB3;
    int i0 = gi * chunk;
    int i1 = min(i0 + chunk, cnt);
#pragma unroll 4
    for (int idx = i0; idx < i1; ++idx) {
      unsigned p = csr[j0 + idx];
      int s = p & SRCMASK;
      int lr = (int)(p >> 27);
      const float4 v = *reinterpret_cast<const float4*>(h2s + (size_t)s * 32 + off);
      atomicAdd(&rows[lr][off + 0], v.x);
      atomicAdd(&rows[lr][off + 1], v.y);
      atomicAdd(&rows[lr][off + 2], v.z);
      atomicAdd(&rows[lr][off + 3], v.w);
    }
  }
  __syncthreads();

  // matvec + segmented max: feature ft = t&127; half (t>>7) takes rows
  // q = half, half+2, ...; per-thread segmented runmax, unioned by atomicMax.
  int ft = t & 127;
  int half = t >> 7;
  float Wreg[32];
#pragma unroll
  for (int k = 0; k < 32; ++k) Wreg[k] = W3[k * 128 + ft];
  float bb = b3[ft];

  if (half < m) {
    int curg = batch[n0 + half];
    float runmax = -INFINITY;
    for (int q = half; q < m; q += 2) {
      int g = batch[n0 + q];
      if (g != curg) {
        atomicMax(&pooled[(size_t)curg * 128 + ft], fenc(runmax));
        runmax = -INFINITY;
        curg = g;
      }
      float acc = 0.f;
#pragma unroll
      for (int k = 0; k < 32; ++k) acc += rows[q][k] * Wreg[k];
      runmax = fmaxf(runmax, dnv[q] * acc + bb);
    }
    atomicMax(&pooled[(size_t)curg * 128 + ft], fenc(runmax));
  }
}

__global__ __launch_bounds__(128) void head_kernel(
    const unsigned* __restrict__ pooled, const float* __restrict__ Wl,
    const float* __restrict__ bl, float* __restrict__ out, int G) {
  int g = blockIdx.x;
  int t = threadIdx.x;  // 128
  float p = fdec(pooled[(size_t)g * 128 + t]);
  __shared__ float red[128];
  __shared__ float sj[3];
  for (int j = 0; j < 3; ++j) {
    red[t] = p * Wl[t * 3 + j];
    __syncthreads();
    for (int k = 64; k > 0; k >>= 1) {
      if (t < k) red[t] += red[t + k];
      __syncthreads();
    }
    if (t == 0) sj[j] = red[0];
    __syncthreads();
  }
  if (t == 0) {
    float l0 = sj[0] + bl[0], l1 = sj[1] + bl[1], l2 = sj[2] + bl[2];
    float m = fmaxf(l0, fmaxf(l1, l2));
    float lse = logf(expf(l0 - m) + expf(l1 - m) + expf(l2 - m));
    out[g * 3 + 0] = l0 - m - lse;
    out[g * 3 + 1] = l1 - m - lse;
    out[g * 3 + 2] = l2 - m - lse;
  }
}

extern "C" void kernel_launch(void* const* d_in, const int* in_sizes, int n_in,
                              void* d_out, int out_size, void* d_ws, size_t ws_size,
                              hipStream_t stream) {
  const float* x = (const float*)d_in[0];
  const int* ei = (const int*)d_in[1];
  const int* batch = (const int*)d_in[2];
  const float* W1 = (const float*)d_in[3];
  const float* b1 = (const float*)d_in[4];
  const float* W2 = (const float*)d_in[5];
  const float* b2 = (const float*)d_in[6];
  const float* W3 = (const float*)d_in[7];
  const float* b3 = (const float*)d_in[8];
  const float* Wl = (const float*)d_in[9];
  const float* bl = (const float*)d_in[10];
  float* out = (float*)d_out;

  const int N = in_sizes[0] / 2;  // x [N,2]
  const int E = in_sizes[1] / 2;  // edge_index [2,E]
  const int G = out_size / 3;     // logits [G,3]

  const int* src = ei;
  const int* dstp = ei + E;

  const int B = (N + BSZ - 1) / BSZ;  // <=256 for N<=131072

  size_t NP = ((size_t)N + 256) & ~(size_t)255;
  size_t EP = ((size_t)E + 255) & ~(size_t)255;

  float* dis = (float*)d_ws;                 // NP
  int* rp = (int*)d_ws + NP;                 // NP
  unsigned* csr = (unsigned*)(rp + NP);      // EP
  unsigned* part = (unsigned*)(csr + EP);    // EP
  int* bucketBase = (int*)(part + EP);       // 512
  int* bucketCursor = bucketBase + 512;      // 512
  int* hist2d = bucketCursor + 512;          // P1_BLOCKS*256
  float* arena = (float*)(hist2d + P1_BLOCKS * 256);

  float* xs = arena;                                        // N*2
  float* h1s = arena + (size_t)2 * N;                       // N*8
  float* h2s = arena + (size_t)10 * N;                      // N*32
  unsigned* pooled = (unsigned*)(arena + (size_t)42 * N);   // G*128

  const int BS = 256;
  auto cdiv = [](long long a, long long b) { return (int)((a + b - 1) / b); };

  // ---- CSR build
  p1_hist_kernel<<<P1_BLOCKS, 256, 0, stream>>>(dstp, hist2d, E);
  p1_scan_kernel<<<1, 256, 0, stream>>>(hist2d, bucketBase, bucketCursor, pooled, B, E, G);
  p2_partition_kernel<<<cdiv(E, P2_TILE), 256, 0, stream>>>(src, dstp, bucketCursor, part, E);
  p3_build_kernel<<<B, BSZ, 0, stream>>>(part, bucketBase, x, xs, dis, rp, csr, N, B, E);

  // ---- fused layers
  layer1_kernel<<<cdiv(N, BS), BS, 0, stream>>>(rp, csr, dis, xs, W1, b1, h1s, N);
  layer2_kernel<<<cdiv(N, BS), BS, 0, stream>>>(rp, csr, dis, h1s, W2, b2, h2s, N);
  layer3_pool_kernel<<<cdiv(N, NB3), 256, 0, stream>>>(rp, csr, dis, h2s, W3, b3, batch, pooled, N);

  // ---- head
  head_kernel<<<G, 128, 0, stream>>>(pooled, Wl, bl, out, G);
}

// Round 12
// 138.754 us; speedup vs baseline: 2.8533x; 2.8533x over previous
//
#include <hip/hip_runtime.h>
#include <hip/hip_fp16.h>

// 3-layer GCN, input-dim aggregation (A(XW) = (AX)W), bucketed CSR build,
// fully fused layers. Layer-3 gather uses per-node register accumulation
// (zero atomics -- R8/R10 showed per-edge LDS atomics are a ~0.7/cyc/CU
// throughput wall) over an fp16 h2s (halves the compulsory cross-XCD
// gather traffic: 128B -> 64B per row).
// R11 bug fixed: h2s row = 32 halves = 4 uint4, pack buffer was sized 2.

#define BSHIFT 9
#define BSZ 512
#define P2_TILE 2048
#define P1_BLOCKS 128
#define SRCMASK 0x1FFFF
#define NB3 32  // nodes per layer3 block

__device__ __forceinline__ unsigned fenc(float x) {
  unsigned b = __float_as_uint(x);
  return (b & 0x80000000u) ? ~b : (b | 0x80000000u);
}
__device__ __forceinline__ float fdec(unsigned k) {
  return (k & 0x80000000u) ? __uint_as_float(k ^ 0x80000000u)
                           : __uint_as_float(~k);
}
__device__ __forceinline__ unsigned pack2(float a, float b) {
  __half2 h = __floats2half2_rn(a, b);
  return *reinterpret_cast<unsigned*>(&h);
}
__device__ __forceinline__ float2 unpack2(unsigned u) {
  __half2 h = *reinterpret_cast<__half2*>(&u);
  return __half22float2(h);
}

// ---------------- CSR build ----------------

__global__ __launch_bounds__(256) void p1_hist_kernel(const int* __restrict__ dst,
                                                      int* __restrict__ hist2d, int E) {
  __shared__ int h[256];
  h[threadIdx.x] = 0;
  __syncthreads();
  for (int e = blockIdx.x * blockDim.x + threadIdx.x; e < E; e += gridDim.x * blockDim.x)
    atomicAdd(&h[dst[e] >> BSHIFT], 1);
  __syncthreads();
  hist2d[blockIdx.x * 256 + threadIdx.x] = h[threadIdx.x];
}

__global__ __launch_bounds__(256) void p1_scan_kernel(const int* __restrict__ hist2d,
                                                      int* __restrict__ bucketBase,
                                                      int* __restrict__ bucketCursor,
                                                      unsigned* __restrict__ pooled,
                                                      int B, int E, int G) {
  __shared__ int s[256];
  int t = threadIdx.x;
  int v = 0;
  for (int b = 0; b < P1_BLOCKS; ++b) v += hist2d[b * 256 + t];
  if (t >= B) v = 0;
  s[t] = v;
  __syncthreads();
  for (int o = 1; o < 256; o <<= 1) {
    int u = (t >= o) ? s[t - o] : 0;
    __syncthreads();
    s[t] += u;
    __syncthreads();
  }
  int excl = s[t] - v;
  bucketBase[t] = excl;
  bucketCursor[t] = excl;
  if (t == 0) bucketBase[256] = E;
  for (int i = t; i < G * 128; i += 256) pooled[i] = 0u;  // fenc key 0 < -inf
}

__global__ __launch_bounds__(256) void p2_partition_kernel(
    const int* __restrict__ src, const int* __restrict__ dst,
    int* __restrict__ bucketCursor, unsigned* __restrict__ part, int E) {
  __shared__ int hist[256];
  __shared__ int lbase[256];
  __shared__ int gbase[256];
  __shared__ int cur[256];
  __shared__ unsigned sbuf[P2_TILE];
  __shared__ unsigned abuf[P2_TILE];
  int t = threadIdx.x;
  int e0 = blockIdx.x * P2_TILE;
  int cnt = min(P2_TILE, E - e0);

  hist[t] = 0;
  __syncthreads();

  int myb[P2_TILE / 256];
  unsigned myp[P2_TILE / 256];
#pragma unroll
  for (int k = 0; k < P2_TILE / 256; ++k) {
    int i = t + k * 256;
    if (i < cnt) {
      int e = e0 + i;
      int d = dst[e];
      int b = d >> BSHIFT;
      myb[k] = b;
      myp[k] = ((unsigned)(d & (BSZ - 1)) << 17) | (unsigned)src[e];
      atomicAdd(&hist[b], 1);
    } else {
      myb[k] = -1;
      myp[k] = 0;
    }
  }
  __syncthreads();

  int v = hist[t];
  lbase[t] = v;
  __syncthreads();
  for (int o = 1; o < 256; o <<= 1) {
    int u = (t >= o) ? lbase[t - o] : 0;
    __syncthreads();
    lbase[t] += u;
    __syncthreads();
  }
  int excl = lbase[t] - v;
  __syncthreads();
  lbase[t] = excl;
  if (v > 0) gbase[t] = atomicAdd(&bucketCursor[t], v);
  cur[t] = 0;
  __syncthreads();

#pragma unroll
  for (int k = 0; k < P2_TILE / 256; ++k) {
    int b = myb[k];
    if (b >= 0) {
      int pos = atomicAdd(&cur[b], 1);
      int li = lbase[b] + pos;
      sbuf[li] = myp[k];
      abuf[li] = (unsigned)(gbase[b] + pos);
    }
  }
  __syncthreads();

#pragma unroll
  for (int k = 0; k < P2_TILE / 256; ++k) {
    int i = t + k * 256;
    if (i < cnt) part[abuf[i]] = sbuf[i];
  }
}

__global__ __launch_bounds__(512) void p3_build_kernel(
    const unsigned* __restrict__ part, const int* __restrict__ bucketBase,
    const float* __restrict__ x, float* __restrict__ xs,
    float* __restrict__ dis, int* __restrict__ rp, unsigned* __restrict__ csr,
    int N, int B, int E) {
  __shared__ int hist[BSZ];
  __shared__ int scn[BSZ];
  int b = blockIdx.x, t = threadIdx.x;
  int base = bucketBase[b], end = bucketBase[b + 1];
  int cnt = end - base;

  hist[t] = 0;
  __syncthreads();
  for (int i = t; i < cnt; i += BSZ) atomicAdd(&hist[part[base + i] >> 17], 1);
  __syncthreads();

  int v = hist[t];
  scn[t] = v;
  __syncthreads();
  for (int o = 1; o < BSZ; o <<= 1) {
    int u = (t >= o) ? scn[t - o] : 0;
    __syncthreads();
    scn[t] += u;
    __syncthreads();
  }
  int excl = scn[t] - v;

  int n = (b << BSHIFT) + t;
  if (n < N) {
    float dn = rsqrtf((float)v + 1.0f);
    dis[n] = dn;
    rp[n] = base + excl;
    float2 xn = *reinterpret_cast<const float2*>(x + 2 * (size_t)n);
    float2 o;
    o.x = dn * xn.x;
    o.y = dn * xn.y;
    *reinterpret_cast<float2*>(xs + 2 * (size_t)n) = o;
  }
  if (b == B - 1 && t == 0) rp[N] = E;

  hist[t] = excl;
  __syncthreads();
  for (int i = t; i < cnt; i += BSZ) {
    unsigned p = part[base + i];
    int pos = atomicAdd(&hist[p >> 17], 1);
    csr[base + pos] = p & SRCMASK;
  }
}

// ---------------- fused layers ----------------

__global__ __launch_bounds__(256) void layer1_kernel(
    const int* __restrict__ rp, const unsigned* __restrict__ csr, const float* __restrict__ dis,
    const float* __restrict__ xs, const float* __restrict__ W1, const float* __restrict__ b1,
    float* __restrict__ h1s, int N) {
  __shared__ float sW[16];
  __shared__ float sb[8];
  int t = threadIdx.x;
  if (t < 16) sW[t] = W1[t];
  if (t < 8) sb[t] = b1[t];
  __syncthreads();
  int n = blockIdx.x * blockDim.x + t;
  if (n >= N) return;
  float2 a = *reinterpret_cast<const float2*>(xs + 2 * (size_t)n);  // self
  int j0 = rp[n], j1 = rp[n + 1];
#pragma unroll 4
  for (int j = j0; j < j1; ++j) {
    int s = csr[j];
    const float2 v = *reinterpret_cast<const float2*>(xs + 2 * (size_t)s);
    a.x += v.x;
    a.y += v.y;
  }
  float dn = dis[n];
  float ax = dn * a.x, ay = dn * a.y;
  float4 o0, o1;
  float* o = &o0.x;
#pragma unroll
  for (int f = 0; f < 8; ++f)
    o[f] = dn * fmaxf(ax * sW[f] + ay * sW[8 + f] + sb[f], 0.f);
  *reinterpret_cast<float4*>(h1s + (size_t)n * 8) = o0;
  *reinterpret_cast<float4*>(h1s + (size_t)n * 8 + 4) = o1;
}

// layer2: thread-per-node; writes h2s as PACKED fp16 (dis-prescaled).
__global__ __launch_bounds__(256) void layer2_kernel(
    const int* __restrict__ rp, const unsigned* __restrict__ csr, const float* __restrict__ dis,
    const float* __restrict__ h1s, const float* __restrict__ W2, const float* __restrict__ b2,
    __half* __restrict__ h2h, int N) {
  __shared__ float sW[256];  // [8][32]
  __shared__ float sb[32];
  int t = threadIdx.x;
  sW[t] = W2[t];
  if (t < 32) sb[t] = b2[t];
  __syncthreads();
  int n = blockIdx.x * blockDim.x + t;
  if (n >= N) return;
  float4 a0 = *reinterpret_cast<const float4*>(h1s + (size_t)n * 8);
  float4 a1 = *reinterpret_cast<const float4*>(h1s + (size_t)n * 8 + 4);
  int j0 = rp[n], j1 = rp[n + 1];
#pragma unroll 4
  for (int j = j0; j < j1; ++j) {
    int s = csr[j];
    const float4 v0 = *reinterpret_cast<const float4*>(h1s + (size_t)s * 8);
    const float4 v1 = *reinterpret_cast<const float4*>(h1s + (size_t)s * 8 + 4);
    a0.x += v0.x; a0.y += v0.y; a0.z += v0.z; a0.w += v0.w;
    a1.x += v1.x; a1.y += v1.y; a1.z += v1.z; a1.w += v1.w;
  }
  float dn = dis[n];
  float a2r[8] = {dn * a0.x, dn * a0.y, dn * a0.z, dn * a0.w,
                  dn * a1.x, dn * a1.y, dn * a1.z, dn * a1.w};
  uint4 pk[4];                       // 16 unsigneds = 32 halves = full row
  unsigned* pw = &pk[0].x;
#pragma unroll
  for (int fc = 0; fc < 8; ++fc) {
    float4 o;
    o.x = sb[fc * 4 + 0]; o.y = sb[fc * 4 + 1]; o.z = sb[fc * 4 + 2]; o.w = sb[fc * 4 + 3];
#pragma unroll
    for (int k = 0; k < 8; ++k) {
      const float4 w = *reinterpret_cast<const float4*>(&sW[k * 32 + fc * 4]);
      float a = a2r[k];
      o.x += a * w.x; o.y += a * w.y; o.z += a * w.z; o.w += a * w.w;
    }
    o.x = dn * fmaxf(o.x, 0.f);
    o.y = dn * fmaxf(o.y, 0.f);
    o.z = dn * fmaxf(o.z, 0.f);
    o.w = dn * fmaxf(o.w, 0.f);
    pw[fc * 2 + 0] = pack2(o.x, o.y);
    pw[fc * 2 + 1] = pack2(o.z, o.w);
  }
  uint4* dst16 = reinterpret_cast<uint4*>(h2h + (size_t)n * 32);
  dst16[0] = pk[0];
  dst16[1] = pk[1];
  dst16[2] = pk[2];
  dst16[3] = pk[3];
}

// layer3 fused: 32 nodes per 128-thread block, 4 threads/node, per-node
// register accumulation over fp16 h2s (16B uint4 = 8 features per thread,
// exclusive ownership -> plain LDS stores, zero atomics), then matvec +
// segmented max-pool.
__global__ __launch_bounds__(128) void layer3_pool_kernel(
    const int* __restrict__ rp, const unsigned* __restrict__ csr, const float* __restrict__ dis,
    const __half* __restrict__ h2h, const float* __restrict__ W3, const float* __restrict__ b3,
    const int* __restrict__ batch, unsigned* __restrict__ pooled, int N) {
  __shared__ float rows[NB3][32];
  __shared__ float dnv[NB3];
  int t = threadIdx.x;
  int gi = t >> 2;          // node slot 0..31
  int q = t & 3;            // feature quarter (8 features)

  int n0 = blockIdx.x * NB3;
  int m = min(NB3, N - n0);

  if (t < m) dnv[t] = dis[n0 + t];

  if (gi < m) {
    int n = n0 + gi;
    uint4 sv = *reinterpret_cast<const uint4*>(h2h + (size_t)n * 32 + q * 8);
    float2 f0 = unpack2(sv.x), f1 = unpack2(sv.y), f2 = unpack2(sv.z), f3 = unpack2(sv.w);
    float acc[8] = {f0.x, f0.y, f1.x, f1.y, f2.x, f2.y, f3.x, f3.y};
    int j0 = rp[n], j1 = rp[n + 1];
#pragma unroll 4
    for (int j = j0; j < j1; ++j) {
      int s = csr[j];
      uint4 v = *reinterpret_cast<const uint4*>(h2h + (size_t)s * 32 + q * 8);
      float2 g0 = unpack2(v.x), g1 = unpack2(v.y), g2 = unpack2(v.z), g3 = unpack2(v.w);
      acc[0] += g0.x; acc[1] += g0.y; acc[2] += g1.x; acc[3] += g1.y;
      acc[4] += g2.x; acc[5] += g2.y; acc[6] += g3.x; acc[7] += g3.y;
    }
#pragma unroll
    for (int i = 0; i < 8; ++i) rows[gi][q * 8 + i] = acc[i];
  }
  __syncthreads();

  // matvec + segmented max: thread t owns output feature t (128 threads)
  float Wreg[32];
#pragma unroll
  for (int k = 0; k < 32; ++k) Wreg[k] = W3[k * 128 + t];
  float bb = b3[t];

  int curg = batch[n0];
  float runmax = -INFINITY;
  for (int r = 0; r < m; ++r) {
    int g = batch[n0 + r];
    if (g != curg) {
      atomicMax(&pooled[(size_t)curg * 128 + t], fenc(runmax));
      runmax = -INFINITY;
      curg = g;
    }
    float acc = 0.f;
#pragma unroll
    for (int k = 0; k < 32; ++k) acc += rows[r][k] * Wreg[k];
    runmax = fmaxf(runmax, dnv[r] * acc + bb);
  }
  atomicMax(&pooled[(size_t)curg * 128 + t], fenc(runmax));
}

__global__ __launch_bounds__(128) void head_kernel(
    const unsigned* __restrict__ pooled, const float* __restrict__ Wl,
    const float* __restrict__ bl, float* __restrict__ out, int G) {
  int g = blockIdx.x;
  int t = threadIdx.x;  // 128
  float p = fdec(pooled[(size_t)g * 128 + t]);
  __shared__ float red[128];
  __shared__ float sj[3];
  for (int j = 0; j < 3; ++j) {
    red[t] = p * Wl[t * 3 + j];
    __syncthreads();
    for (int k = 64; k > 0; k >>= 1) {
      if (t < k) red[t] += red[t + k];
      __syncthreads();
    }
    if (t == 0) sj[j] = red[0];
    __syncthreads();
  }
  if (t == 0) {
    float l0 = sj[0] + bl[0], l1 = sj[1] + bl[1], l2 = sj[2] + bl[2];
    float m = fmaxf(l0, fmaxf(l1, l2));
    float lse = logf(expf(l0 - m) + expf(l1 - m) + expf(l2 - m));
    out[g * 3 + 0] = l0 - m - lse;
    out[g * 3 + 1] = l1 - m - lse;
    out[g * 3 + 2] = l2 - m - lse;
  }
}

extern "C" void kernel_launch(void* const* d_in, const int* in_sizes, int n_in,
                              void* d_out, int out_size, void* d_ws, size_t ws_size,
                              hipStream_t stream) {
  const float* x = (const float*)d_in[0];
  const int* ei = (const int*)d_in[1];
  const int* batch = (const int*)d_in[2];
  const float* W1 = (const float*)d_in[3];
  const float* b1 = (const float*)d_in[4];
  const float* W2 = (const float*)d_in[5];
  const float* b2 = (const float*)d_in[6];
  const float* W3 = (const float*)d_in[7];
  const float* b3 = (const float*)d_in[8];
  const float* Wl = (const float*)d_in[9];
  const float* bl = (const float*)d_in[10];
  float* out = (float*)d_out;

  const int N = in_sizes[0] / 2;  // x [N,2]
  const int E = in_sizes[1] / 2;  // edge_index [2,E]
  const int G = out_size / 3;     // logits [G,3]

  const int* src = ei;
  const int* dstp = ei + E;

  const int B = (N + BSZ - 1) / BSZ;  // <=256 for N<=131072

  size_t NP = ((size_t)N + 256) & ~(size_t)255;
  size_t EP = ((size_t)E + 255) & ~(size_t)255;

  float* dis = (float*)d_ws;                 // NP
  int* rp = (int*)d_ws + NP;                 // NP
  unsigned* csr = (unsigned*)(rp + NP);      // EP
  unsigned* part = (unsigned*)(csr + EP);    // EP
  int* bucketBase = (int*)(part + EP);       // 512
  int* bucketCursor = bucketBase + 512;      // 512
  int* hist2d = bucketCursor + 512;          // P1_BLOCKS*256
  float* arena = (float*)(hist2d + P1_BLOCKS * 256);

  float* xs = arena;                                        // N*2 f32
  float* h1s = arena + (size_t)2 * N;                       // N*8 f32
  __half* h2h = (__half*)(arena + (size_t)10 * N);          // N*32 fp16 (= N*16 f32)
  unsigned* pooled = (unsigned*)(arena + (size_t)26 * N);   // G*128

  const int BS = 256;
  auto cdiv = [](long long a, long long b) { return (int)((a + b - 1) / b); };

  // ---- CSR build
  p1_hist_kernel<<<P1_BLOCKS, 256, 0, stream>>>(dstp, hist2d, E);
  p1_scan_kernel<<<1, 256, 0, stream>>>(hist2d, bucketBase, bucketCursor, pooled, B, E, G);
  p2_partition_kernel<<<cdiv(E, P2_TILE), 256, 0, stream>>>(src, dstp, bucketCursor, part, E);
  p3_build_kernel<<<B, BSZ, 0, stream>>>(part, bucketBase, x, xs, dis, rp, csr, N, B, E);

  // ---- fused layers
  layer1_kernel<<<cdiv(N, BS), BS, 0, stream>>>(rp, csr, dis, xs, W1, b1, h1s, N);
  layer2_kernel<<<cdiv(N, BS), BS, 0, stream>>>(rp, csr, dis, h1s, W2, b2, h2h, N);
  layer3_pool_kernel<<<cdiv(N, NB3), 128, 0, stream>>>(rp, csr, dis, h2h, W3, b3, batch, pooled, N);

  // ---- head
  head_kernel<<<G, 128, 0, stream>>>(pooled, Wl, bl, out, G);
}

// Round 13
// 134.108 us; speedup vs baseline: 2.9522x; 1.0346x over previous
//
#include <hip/hip_runtime.h>
#include <hip/hip_fp16.h>

// 3-layer GCN, input-dim aggregation (A(XW) = (AX)W), bucketed CSR build,
// fully fused layers. All gather-source arrays stored fp16 (accumulate fp32):
//   xs  [N,2]  fp16 ( 4 B/row) -- layer1 gather
//   h1s [N,8]  fp16 (16 B/row) -- layer2 gather
//   h2s [N,32] fp16 (64 B/row) -- layer3 gather
// Per-node register accumulation everywhere (zero atomics in layers; R8/R10
// showed per-edge LDS atomics are a throughput wall).

#define BSHIFT 9
#define BSZ 512
#define P2_TILE 2048
#define P1_BLOCKS 128
#define SRCMASK 0x1FFFF
#define NB3 32  // nodes per layer3 block

__device__ __forceinline__ unsigned fenc(float x) {
  unsigned b = __float_as_uint(x);
  return (b & 0x80000000u) ? ~b : (b | 0x80000000u);
}
__device__ __forceinline__ float fdec(unsigned k) {
  return (k & 0x80000000u) ? __uint_as_float(k ^ 0x80000000u)
                           : __uint_as_float(~k);
}
__device__ __forceinline__ unsigned pack2(float a, float b) {
  __half2 h = __floats2half2_rn(a, b);
  return *reinterpret_cast<unsigned*>(&h);
}
__device__ __forceinline__ float2 unpack2(unsigned u) {
  __half2 h = *reinterpret_cast<__half2*>(&u);
  return __half22float2(h);
}

// ---------------- CSR build ----------------

__global__ __launch_bounds__(256) void p1_hist_kernel(const int* __restrict__ dst,
                                                      int* __restrict__ hist2d, int E) {
  __shared__ int h[256];
  h[threadIdx.x] = 0;
  __syncthreads();
  for (int e = blockIdx.x * blockDim.x + threadIdx.x; e < E; e += gridDim.x * blockDim.x)
    atomicAdd(&h[dst[e] >> BSHIFT], 1);
  __syncthreads();
  hist2d[blockIdx.x * 256 + threadIdx.x] = h[threadIdx.x];
}

__global__ __launch_bounds__(256) void p1_scan_kernel(const int* __restrict__ hist2d,
                                                      int* __restrict__ bucketBase,
                                                      int* __restrict__ bucketCursor,
                                                      unsigned* __restrict__ pooled,
                                                      int B, int E, int G) {
  __shared__ int s[256];
  int t = threadIdx.x;
  int v = 0;
  for (int b = 0; b < P1_BLOCKS; ++b) v += hist2d[b * 256 + t];
  if (t >= B) v = 0;
  s[t] = v;
  __syncthreads();
  for (int o = 1; o < 256; o <<= 1) {
    int u = (t >= o) ? s[t - o] : 0;
    __syncthreads();
    s[t] += u;
    __syncthreads();
  }
  int excl = s[t] - v;
  bucketBase[t] = excl;
  bucketCursor[t] = excl;
  if (t == 0) bucketBase[256] = E;
  for (int i = t; i < G * 128; i += 256) pooled[i] = 0u;  // fenc key 0 < -inf
}

__global__ __launch_bounds__(256) void p2_partition_kernel(
    const int* __restrict__ src, const int* __restrict__ dst,
    int* __restrict__ bucketCursor, unsigned* __restrict__ part, int E) {
  __shared__ int hist[256];
  __shared__ int lbase[256];
  __shared__ int gbase[256];
  __shared__ int cur[256];
  __shared__ unsigned sbuf[P2_TILE];
  __shared__ unsigned abuf[P2_TILE];
  int t = threadIdx.x;
  int e0 = blockIdx.x * P2_TILE;
  int cnt = min(P2_TILE, E - e0);

  hist[t] = 0;
  __syncthreads();

  int myb[P2_TILE / 256];
  unsigned myp[P2_TILE / 256];
#pragma unroll
  for (int k = 0; k < P2_TILE / 256; ++k) {
    int i = t + k * 256;
    if (i < cnt) {
      int e = e0 + i;
      int d = dst[e];
      int b = d >> BSHIFT;
      myb[k] = b;
      myp[k] = ((unsigned)(d & (BSZ - 1)) << 17) | (unsigned)src[e];
      atomicAdd(&hist[b], 1);
    } else {
      myb[k] = -1;
      myp[k] = 0;
    }
  }
  __syncthreads();

  int v = hist[t];
  lbase[t] = v;
  __syncthreads();
  for (int o = 1; o < 256; o <<= 1) {
    int u = (t >= o) ? lbase[t - o] : 0;
    __syncthreads();
    lbase[t] += u;
    __syncthreads();
  }
  int excl = lbase[t] - v;
  __syncthreads();
  lbase[t] = excl;
  if (v > 0) gbase[t] = atomicAdd(&bucketCursor[t], v);
  cur[t] = 0;
  __syncthreads();

#pragma unroll
  for (int k = 0; k < P2_TILE / 256; ++k) {
    int b = myb[k];
    if (b >= 0) {
      int pos = atomicAdd(&cur[b], 1);
      int li = lbase[b] + pos;
      sbuf[li] = myp[k];
      abuf[li] = (unsigned)(gbase[b] + pos);
    }
  }
  __syncthreads();

#pragma unroll
  for (int k = 0; k < P2_TILE / 256; ++k) {
    int i = t + k * 256;
    if (i < cnt) part[abuf[i]] = sbuf[i];
  }
}

__global__ __launch_bounds__(512) void p3_build_kernel(
    const unsigned* __restrict__ part, const int* __restrict__ bucketBase,
    const float* __restrict__ x, unsigned* __restrict__ xsh,
    float* __restrict__ dis, int* __restrict__ rp, unsigned* __restrict__ csr,
    int N, int B, int E) {
  __shared__ int hist[BSZ];
  __shared__ int scn[BSZ];
  int b = blockIdx.x, t = threadIdx.x;
  int base = bucketBase[b], end = bucketBase[b + 1];
  int cnt = end - base;

  hist[t] = 0;
  __syncthreads();
  for (int i = t; i < cnt; i += BSZ) atomicAdd(&hist[part[base + i] >> 17], 1);
  __syncthreads();

  int v = hist[t];
  scn[t] = v;
  __syncthreads();
  for (int o = 1; o < BSZ; o <<= 1) {
    int u = (t >= o) ? scn[t - o] : 0;
    __syncthreads();
    scn[t] += u;
    __syncthreads();
  }
  int excl = scn[t] - v;

  int n = (b << BSHIFT) + t;
  if (n < N) {
    float dn = rsqrtf((float)v + 1.0f);
    dis[n] = dn;
    rp[n] = base + excl;
    float2 xn = *reinterpret_cast<const float2*>(x + 2 * (size_t)n);
    xsh[n] = pack2(dn * xn.x, dn * xn.y);  // fp16 pre-scaled x
  }
  if (b == B - 1 && t == 0) rp[N] = E;

  hist[t] = excl;
  __syncthreads();
  for (int i = t; i < cnt; i += BSZ) {
    unsigned p = part[base + i];
    int pos = atomicAdd(&hist[p >> 17], 1);
    csr[base + pos] = p & SRCMASK;
  }
}

// ---------------- fused layers ----------------

// layer1: thread-per-node; gathers fp16 xs (4B/edge); writes fp16 h1s (16B).
__global__ __launch_bounds__(256) void layer1_kernel(
    const int* __restrict__ rp, const unsigned* __restrict__ csr, const float* __restrict__ dis,
    const unsigned* __restrict__ xsh, const float* __restrict__ W1, const float* __restrict__ b1,
    uint4* __restrict__ h1h, int N) {
  __shared__ float sW[16];
  __shared__ float sb[8];
  int t = threadIdx.x;
  if (t < 16) sW[t] = W1[t];
  if (t < 8) sb[t] = b1[t];
  __syncthreads();
  int n = blockIdx.x * blockDim.x + t;
  if (n >= N) return;
  float2 a = unpack2(xsh[n]);  // self
  int j0 = rp[n], j1 = rp[n + 1];
#pragma unroll 4
  for (int j = j0; j < j1; ++j) {
    const float2 v = unpack2(xsh[csr[j]]);
    a.x += v.x;
    a.y += v.y;
  }
  float dn = dis[n];
  float ax = dn * a.x, ay = dn * a.y;
  uint4 pk;
  unsigned* pw = &pk.x;
#pragma unroll
  for (int fc = 0; fc < 4; ++fc) {
    float e0 = dn * fmaxf(ax * sW[fc * 2 + 0] + ay * sW[8 + fc * 2 + 0] + sb[fc * 2 + 0], 0.f);
    float e1 = dn * fmaxf(ax * sW[fc * 2 + 1] + ay * sW[8 + fc * 2 + 1] + sb[fc * 2 + 1], 0.f);
    pw[fc] = pack2(e0, e1);
  }
  h1h[n] = pk;
}

// layer2: thread-per-node; gathers fp16 h1s (one uint4/edge); writes fp16 h2s.
__global__ __launch_bounds__(256) void layer2_kernel(
    const int* __restrict__ rp, const unsigned* __restrict__ csr, const float* __restrict__ dis,
    const uint4* __restrict__ h1h, const float* __restrict__ W2, const float* __restrict__ b2,
    __half* __restrict__ h2h, int N) {
  __shared__ float sW[256];  // [8][32]
  __shared__ float sb[32];
  int t = threadIdx.x;
  sW[t] = W2[t];
  if (t < 32) sb[t] = b2[t];
  __syncthreads();
  int n = blockIdx.x * blockDim.x + t;
  if (n >= N) return;
  float acc[8];
  {
    uint4 sv = h1h[n];
    float2 f0 = unpack2(sv.x), f1 = unpack2(sv.y), f2 = unpack2(sv.z), f3 = unpack2(sv.w);
    acc[0] = f0.x; acc[1] = f0.y; acc[2] = f1.x; acc[3] = f1.y;
    acc[4] = f2.x; acc[5] = f2.y; acc[6] = f3.x; acc[7] = f3.y;
  }
  int j0 = rp[n], j1 = rp[n + 1];
#pragma unroll 4
  for (int j = j0; j < j1; ++j) {
    uint4 v = h1h[csr[j]];
    float2 g0 = unpack2(v.x), g1 = unpack2(v.y), g2 = unpack2(v.z), g3 = unpack2(v.w);
    acc[0] += g0.x; acc[1] += g0.y; acc[2] += g1.x; acc[3] += g1.y;
    acc[4] += g2.x; acc[5] += g2.y; acc[6] += g3.x; acc[7] += g3.y;
  }
  float dn = dis[n];
#pragma unroll
  for (int k = 0; k < 8; ++k) acc[k] *= dn;
  uint4 pk[4];  // 16 unsigneds = 32 halves = full row
  unsigned* pw = &pk[0].x;
#pragma unroll
  for (int fc = 0; fc < 8; ++fc) {
    float4 o;
    o.x = sb[fc * 4 + 0]; o.y = sb[fc * 4 + 1]; o.z = sb[fc * 4 + 2]; o.w = sb[fc * 4 + 3];
#pragma unroll
    for (int k = 0; k < 8; ++k) {
      const float4 w = *reinterpret_cast<const float4*>(&sW[k * 32 + fc * 4]);
      float a = acc[k];
      o.x += a * w.x; o.y += a * w.y; o.z += a * w.z; o.w += a * w.w;
    }
    o.x = dn * fmaxf(o.x, 0.f);
    o.y = dn * fmaxf(o.y, 0.f);
    o.z = dn * fmaxf(o.z, 0.f);
    o.w = dn * fmaxf(o.w, 0.f);
    pw[fc * 2 + 0] = pack2(o.x, o.y);
    pw[fc * 2 + 1] = pack2(o.z, o.w);
  }
  uint4* dst16 = reinterpret_cast<uint4*>(h2h + (size_t)n * 32);
  dst16[0] = pk[0];
  dst16[1] = pk[1];
  dst16[2] = pk[2];
  dst16[3] = pk[3];
}

// layer3 fused: 32 nodes per 128-thread block, 4 threads/node, per-node
// register accumulation over fp16 h2s, then matvec + segmented max-pool.
__global__ __launch_bounds__(128) void layer3_pool_kernel(
    const int* __restrict__ rp, const unsigned* __restrict__ csr, const float* __restrict__ dis,
    const __half* __restrict__ h2h, const float* __restrict__ W3, const float* __restrict__ b3,
    const int* __restrict__ batch, unsigned* __restrict__ pooled, int N) {
  __shared__ float rows[NB3][32];
  __shared__ float dnv[NB3];
  int t = threadIdx.x;
  int gi = t >> 2;          // node slot 0..31
  int q = t & 3;            // feature quarter (8 features)

  int n0 = blockIdx.x * NB3;
  int m = min(NB3, N - n0);

  if (t < m) dnv[t] = dis[n0 + t];

  if (gi < m) {
    int n = n0 + gi;
    uint4 sv = *reinterpret_cast<const uint4*>(h2h + (size_t)n * 32 + q * 8);
    float2 f0 = unpack2(sv.x), f1 = unpack2(sv.y), f2 = unpack2(sv.z), f3 = unpack2(sv.w);
    float acc[8] = {f0.x, f0.y, f1.x, f1.y, f2.x, f2.y, f3.x, f3.y};
    int j0 = rp[n], j1 = rp[n + 1];
#pragma unroll 4
    for (int j = j0; j < j1; ++j) {
      int s = csr[j];
      uint4 v = *reinterpret_cast<const uint4*>(h2h + (size_t)s * 32 + q * 8);
      float2 g0 = unpack2(v.x), g1 = unpack2(v.y), g2 = unpack2(v.z), g3 = unpack2(v.w);
      acc[0] += g0.x; acc[1] += g0.y; acc[2] += g1.x; acc[3] += g1.y;
      acc[4] += g2.x; acc[5] += g2.y; acc[6] += g3.x; acc[7] += g3.y;
    }
#pragma unroll
    for (int i = 0; i < 8; ++i) rows[gi][q * 8 + i] = acc[i];
  }
  __syncthreads();

  // matvec + segmented max: thread t owns output feature t (128 threads)
  float Wreg[32];
#pragma unroll
  for (int k = 0; k < 32; ++k) Wreg[k] = W3[k * 128 + t];
  float bb = b3[t];

  int curg = batch[n0];
  float runmax = -INFINITY;
  for (int r = 0; r < m; ++r) {
    int g = batch[n0 + r];
    if (g != curg) {
      atomicMax(&pooled[(size_t)curg * 128 + t], fenc(runmax));
      runmax = -INFINITY;
      curg = g;
    }
    float acc = 0.f;
#pragma unroll
    for (int k = 0; k < 32; ++k) acc += rows[r][k] * Wreg[k];
    runmax = fmaxf(runmax, dnv[r] * acc + bb);
  }
  atomicMax(&pooled[(size_t)curg * 128 + t], fenc(runmax));
}

__global__ __launch_bounds__(128) void head_kernel(
    const unsigned* __restrict__ pooled, const float* __restrict__ Wl,
    const float* __restrict__ bl, float* __restrict__ out, int G) {
  int g = blockIdx.x;
  int t = threadIdx.x;  // 128
  float p = fdec(pooled[(size_t)g * 128 + t]);
  __shared__ float red[128];
  __shared__ float sj[3];
  for (int j = 0; j < 3; ++j) {
    red[t] = p * Wl[t * 3 + j];
    __syncthreads();
    for (int k = 64; k > 0; k >>= 1) {
      if (t < k) red[t] += red[t + k];
      __syncthreads();
    }
    if (t == 0) sj[j] = red[0];
    __syncthreads();
  }
  if (t == 0) {
    float l0 = sj[0] + bl[0], l1 = sj[1] + bl[1], l2 = sj[2] + bl[2];
    float m = fmaxf(l0, fmaxf(l1, l2));
    float lse = logf(expf(l0 - m) + expf(l1 - m) + expf(l2 - m));
    out[g * 3 + 0] = l0 - m - lse;
    out[g * 3 + 1] = l1 - m - lse;
    out[g * 3 + 2] = l2 - m - lse;
  }
}

extern "C" void kernel_launch(void* const* d_in, const int* in_sizes, int n_in,
                              void* d_out, int out_size, void* d_ws, size_t ws_size,
                              hipStream_t stream) {
  const float* x = (const float*)d_in[0];
  const int* ei = (const int*)d_in[1];
  const int* batch = (const int*)d_in[2];
  const float* W1 = (const float*)d_in[3];
  const float* b1 = (const float*)d_in[4];
  const float* W2 = (const float*)d_in[5];
  const float* b2 = (const float*)d_in[6];
  const float* W3 = (const float*)d_in[7];
  const float* b3 = (const float*)d_in[8];
  const float* Wl = (const float*)d_in[9];
  const float* bl = (const float*)d_in[10];
  float* out = (float*)d_out;

  const int N = in_sizes[0] / 2;  // x [N,2]
  const int E = in_sizes[1] / 2;  // edge_index [2,E]
  const int G = out_size / 3;     // logits [G,3]

  const int* src = ei;
  const int* dstp = ei + E;

  const int B = (N + BSZ - 1) / BSZ;  // <=256 for N<=131072

  size_t NP = ((size_t)N + 256) & ~(size_t)255;
  size_t EP = ((size_t)E + 255) & ~(size_t)255;

  float* dis = (float*)d_ws;                 // NP
  int* rp = (int*)d_ws + NP;                 // NP
  unsigned* csr = (unsigned*)(rp + NP);      // EP
  unsigned* part = (unsigned*)(csr + EP);    // EP
  int* bucketBase = (int*)(part + EP);       // 512
  int* bucketCursor = bucketBase + 512;      // 512
  int* hist2d = bucketCursor + 512;          // P1_BLOCKS*256
  float* arena = (float*)(hist2d + P1_BLOCKS * 256);

  unsigned* xsh = (unsigned*)arena;                         // N uints  (fp16 x2)
  uint4* h1h = (uint4*)(arena + (size_t)N);                 // N uint4  (fp16 x8)
  __half* h2h = (__half*)(arena + (size_t)5 * N);           // N*32 fp16
  unsigned* pooled = (unsigned*)(arena + (size_t)21 * N);   // G*128

  const int BS = 256;
  auto cdiv = [](long long a, long long b) { return (int)((a + b - 1) / b); };

  // ---- CSR build
  p1_hist_kernel<<<P1_BLOCKS, 256, 0, stream>>>(dstp, hist2d, E);
  p1_scan_kernel<<<1, 256, 0, stream>>>(hist2d, bucketBase, bucketCursor, pooled, B, E, G);
  p2_partition_kernel<<<cdiv(E, P2_TILE), 256, 0, stream>>>(src, dstp, bucketCursor, part, E);
  p3_build_kernel<<<B, BSZ, 0, stream>>>(part, bucketBase, x, xsh, dis, rp, csr, N, B, E);

  // ---- fused layers
  layer1_kernel<<<cdiv(N, BS), BS, 0, stream>>>(rp, csr, dis, xsh, W1, b1, h1h, N);
  layer2_kernel<<<cdiv(N, BS), BS, 0, stream>>>(rp, csr, dis, h1h, W2, b2, h2h, N);
  layer3_pool_kernel<<<cdiv(N, NB3), 128, 0, stream>>>(rp, csr, dis, h2h, W3, b3, batch, pooled, N);

  // ---- head
  head_kernel<<<G, 128, 0, stream>>>(pooled, Wl, bl, out, G);
}